// Round 3
// baseline (294.429 us; speedup 1.0000x reference)
//
#include <hip/hip_runtime.h>
#include <hip/hip_bf16.h>

typedef unsigned short u16;
typedef __attribute__((ext_vector_type(8))) short frag8;   // 8 bf16 (4 VGPRs)
typedef __attribute__((ext_vector_type(4))) float f32x4;   // MFMA accumulator

// Orthonormal DCT-II, first 4 rows of the 8-point basis: D4[k][i]
__constant__ float D4[4][8] = {
  { 0.3535533906f,  0.3535533906f,  0.3535533906f,  0.3535533906f,
    0.3535533906f,  0.3535533906f,  0.3535533906f,  0.3535533906f},
  { 0.4903926402f,  0.4157348062f,  0.2777851165f,  0.0975451610f,
   -0.0975451610f, -0.2777851165f, -0.4157348062f, -0.4903926402f},
  { 0.4619397663f,  0.1913417162f, -0.1913417162f, -0.4619397663f,
   -0.4619397663f, -0.1913417162f,  0.1913417162f,  0.4619397663f},
  { 0.4157348062f, -0.0975451610f, -0.4903926402f, -0.2777851165f,
    0.2777851165f,  0.4903926402f,  0.0975451610f, -0.4157348062f}
};

__device__ __forceinline__ u16 f2bf(float f) {
  unsigned u; __builtin_memcpy(&u, &f, 4);
  u = (u + 0x7FFFu + ((u >> 16) & 1u)) >> 16;   // RNE
  return (u16)u;
}

// LDS layout (bytes):
//   h     : [64][264] bf16 @ 0      (33792 B)  row pad +8 -> cheap b128 reads
//   feats : [64][20]  f32  @ 33792  (5120 B)   dead after phase 3
//   gray  : [8][516]  f32  @ 38912  (16512 B)  dead after phase 2
//   embT  : [64][68]  f32  @ 33792  (17408 B)  aliases feats+gray (both dead)
#define SMEM_BYTES 55424

__global__ __launch_bounds__(256, 2)
void dct_mlp_fused(const float* __restrict__ x,
                   const float* __restrict__ W1, const float* __restrict__ b1,
                   const float* __restrict__ W2, const float* __restrict__ b2,
                   float* __restrict__ out) {
  __shared__ __align__(16) char smem[SMEM_BYTES];
  u16*   hS    = (u16*)smem;               // [64][264]
  float* featS = (float*)(smem + 33792);   // [64][20]
  float* grayS = (float*)(smem + 38912);   // [8][516]
  float* embS  = (float*)(smem + 33792);   // [64][68]

  const int t    = threadIdx.x;
  const int lane = t & 63;
  const int w    = t >> 6;          // wave 0..3
  const int quad = lane >> 4;       // 0..3
  const int l16  = lane & 15;

  const int gy = blockIdx.x;        // 0..63
  const int b  = blockIdx.y;        // 0..31

  // ---- Prefetch weight fragments (independent of LDS phases) ----
  // GEMM1 B-frags: wave w covers n-tiles w*4..w*4+3 of N=256; K=16 padded to 32.
  frag8 bW1[4];
  float b1v[4];
  for (int nt = 0; nt < 4; ++nt) {
    int n = (w * 4 + nt) * 16 + l16;
    frag8 f;
    for (int j = 0; j < 8; ++j) {
      int k = quad * 8 + j;
      f[j] = (k < 16) ? (short)f2bf(W1[k * 256 + n]) : (short)0;
    }
    bW1[nt] = f;
    b1v[nt] = b1[n];
  }
  // GEMM2 B-frags: wave w owns n-tile w of N=64; K=256 in 8 steps of 32.
  frag8 bW2[8];
  const int n3 = w * 16 + l16;
  for (int s = 0; s < 8; ++s) {
    frag8 f;
    for (int j = 0; j < 8; ++j) {
      int c = s * 32 + quad * 8 + j;
      f[j] = (short)f2bf(W2[c * 64 + n3]);
    }
    bW2[s] = f;
  }
  const float b2v = b2[n3];

  // ---- Phase 1: grayscale into LDS (8 rows x 512 cols, fp32) ----
  {
    const int r  = t >> 5;          // row 0..7
    const int c0 = (t & 31) * 16;   // col chunk of 16
    const size_t base = (((size_t)b * 3) * 512 + (size_t)gy * 8 + r) * 512 + c0;
    const float4* pR = (const float4*)(x + base);
    const float4* pG = (const float4*)(x + base + 512 * 512);
    const float4* pB = (const float4*)(x + base + 2 * 512 * 512);
    float* gdst = grayS + r * 516 + c0;
    #pragma unroll
    for (int q = 0; q < 4; ++q) {
      float4 a = pR[q], g = pG[q], c = pB[q];
      gdst[4*q+0] = 0.299f * a.x + 0.587f * g.x + 0.114f * c.x;
      gdst[4*q+1] = 0.299f * a.y + 0.587f * g.y + 0.114f * c.y;
      gdst[4*q+2] = 0.299f * a.z + 0.587f * g.z + 0.114f * c.z;
      gdst[4*q+3] = 0.299f * a.w + 0.587f * g.w + 0.114f * c.w;
    }
  }
  __syncthreads();

  // ---- Phase 2: DCT -> feats (4 threads per patch, one coeff-row each) ----
  {
    const int p  = t >> 2;   // patch (gx) 0..63
    const int kr = t & 3;    // coeff row
    float tmp[8] = {0,0,0,0,0,0,0,0};
    for (int i = 0; i < 8; ++i) {
      const float* row = grayS + i * 516 + p * 8;
      float d = D4[kr][i];
      #pragma unroll
      for (int j = 0; j < 8; ++j) tmp[j] = fmaf(d, row[j], tmp[j]);
    }
    float* fo = featS + p * 20 + kr * 4;
    #pragma unroll
    for (int l = 0; l < 4; ++l) {
      float s = 0.f;
      #pragma unroll
      for (int j = 0; j < 8; ++j) s = fmaf(tmp[j], D4[l][j], s);
      fo[l] = s;
    }
  }
  __syncthreads();

  // ---- Phase 3: GEMM1 (feats[64x16] @ W1[16x256] + b1, relu) -> h bf16 LDS ----
  for (int mt = 0; mt < 4; ++mt) {
    frag8 a = {0,0,0,0,0,0,0,0};
    if (quad < 2) {
      const float* fp = featS + (mt * 16 + l16) * 20 + quad * 8;
      #pragma unroll
      for (int j = 0; j < 8; ++j) a[j] = (short)f2bf(fp[j]);
    }
    for (int nt = 0; nt < 4; ++nt) {
      f32x4 acc = {b1v[nt], b1v[nt], b1v[nt], b1v[nt]};
      acc = __builtin_amdgcn_mfma_f32_16x16x32_bf16(a, bW1[nt], acc, 0, 0, 0);
      int n = (w * 4 + nt) * 16 + l16;
      #pragma unroll
      for (int rg = 0; rg < 4; ++rg) {
        float v = acc[rg];
        v = v > 0.f ? v : 0.f;
        int m = mt * 16 + quad * 4 + rg;
        hS[m * 264 + n] = f2bf(v);
      }
    }
  }
  __syncthreads();

  // ---- Phase 4: GEMM2 (h[64x256] @ W2[256x64] + b2) -> embT (fp32 LDS) ----
  // embS aliases featS/gray: featS reads completed before the barrier above.
  f32x4 accs[4];
  for (int mt = 0; mt < 4; ++mt) {
    f32x4 acc = {b2v, b2v, b2v, b2v};
    const u16* hrow = hS + (mt * 16 + l16) * 264;
    #pragma unroll
    for (int s = 0; s < 8; ++s) {
      frag8 a = *(const frag8*)(hrow + s * 32 + quad * 8);  // ds_read_b128
      acc = __builtin_amdgcn_mfma_f32_16x16x32_bf16(a, bW2[s], acc, 0, 0, 0);
    }
    accs[mt] = acc;
  }
  __syncthreads();   // make sure all featS/gray readers are done before alias write
  for (int mt = 0; mt < 4; ++mt) {
    #pragma unroll
    for (int rg = 0; rg < 4; ++rg) {
      int gx = mt * 16 + quad * 4 + rg;
      embS[n3 * 68 + gx] = accs[mt][rg];
    }
  }
  __syncthreads();

  // ---- Phase 5: coalesced fp32 store: out[b][ch][gy][gx] ----
  {
    const int ch = t >> 2;   // 0..63
    const int cc = t & 3;    // 16-wide gx chunk
    const float* src = embS + ch * 68 + cc * 16;
    float* dst = out + ((((size_t)b * 64 + ch) * 64) + gy) * 64 + cc * 16;
    #pragma unroll
    for (int q = 0; q < 4; ++q)
      ((float4*)dst)[q] = ((const float4*)src)[q];
  }
}

extern "C" void kernel_launch(void* const* d_in, const int* in_sizes, int n_in,
                              void* d_out, int out_size, void* d_ws, size_t ws_size,
                              hipStream_t stream) {
  const float* x  = (const float*)d_in[0];
  const float* W1 = (const float*)d_in[1];
  const float* b1 = (const float*)d_in[2];
  const float* W2 = (const float*)d_in[3];
  const float* b2 = (const float*)d_in[4];
  float* out = (float*)d_out;
  dim3 grid(64, 32, 1);   // (gy, b)
  dct_mlp_fused<<<grid, dim3(256, 1, 1), 0, stream>>>(x, W1, b1, W2, b2, out);
}

// Round 4
// 216.730 us; speedup vs baseline: 1.3585x; 1.3585x over previous
//
#include <hip/hip_runtime.h>

typedef unsigned short u16;
typedef __attribute__((ext_vector_type(8))) short frag8;   // 8 bf16 (4 VGPRs)
typedef __attribute__((ext_vector_type(4))) float f32x4;   // MFMA accumulator

__device__ __forceinline__ u16 f2bf(float f) {
  unsigned u; __builtin_memcpy(&u, &f, 4);
  u = (u + 0x7FFFu + ((u >> 16) & 1u)) >> 16;   // RNE
  return (u16)u;
}
__device__ __forceinline__ float sel4(int s, float a, float b, float c, float d) {
  return s == 0 ? a : (s == 1 ? b : (s == 2 ? c : d));
}

#define FSTRIDE 24    // feats row stride (bf16 units): 48 B, keeps b128 reads 16-B aligned
#define HSTRIDE 264   // h row stride (bf16 units), +8 pad
// LDS: hS [64][264] bf16 @ 0 (33792 B); feats [64][24] bf16 @ 33792 (3072 B)
#define SMEM_BYTES 36864

__global__ __launch_bounds__(256, 4)
void dct_mlp_fused(const float* __restrict__ x,
                   const float* __restrict__ W1, const float* __restrict__ b1,
                   const float* __restrict__ W2, const float* __restrict__ b2,
                   float* __restrict__ out) {
  __shared__ __align__(16) char smem[SMEM_BYTES];
  u16* hS    = (u16*)smem;               // [64][264]
  u16* featS = (u16*)(smem + 33792);     // [64][24]

  const int t    = threadIdx.x;
  const int lane = t & 63;
  const int w    = t >> 6;          // wave 0..3
  const int quad = lane >> 4;       // 0..3
  const int l16  = lane & 15;

  const int gy = blockIdx.x;        // 0..63
  const int b  = blockIdx.y;        // 0..31

  // ---- Weight fragment prefetch (L2-hot after first blocks; overlaps DCT) ----
  frag8 bW1[4];
  float b1v[4];
  for (int nt = 0; nt < 4; ++nt) {
    int n = (w * 4 + nt) * 16 + l16;
    frag8 f;
    for (int j = 0; j < 8; ++j) {
      int k = quad * 8 + j;
      f[j] = (k < 16) ? (short)f2bf(W1[k * 256 + n]) : (short)0;
    }
    bW1[nt] = f;
    b1v[nt] = b1[n];
  }
  frag8 bW2[8];
  const int n3 = w * 16 + l16;      // GEMM2 output channel
  for (int s = 0; s < 8; ++s) {
    frag8 f;
    for (int j = 0; j < 8; ++j) {
      int c = s * 32 + quad * 8 + j;
      f[j] = (short)f2bf(W2[c * 64 + n3]);
    }
    bW2[s] = f;
  }
  const float b2v = b2[n3];

  // ---- Phase A: register DCT, straight from global (no LDS gray) ----
  // thread (p = t>>2, kr = t&3): coeff row kr of patch p. The 4 kr-threads of a
  // patch re-read the same pixels; dup-lane + L1/L2 absorb it (HBM reads x once).
  {
    const int p  = t >> 2;
    const int kr = t & 3;
    // D4[kr][i] via cndmask select (no runtime-indexed constant-mem loads)
    float dk[8];
    dk[0] = sel4(kr, 0.35355339f,  0.49039264f,  0.46193977f,  0.41573481f);
    dk[1] = sel4(kr, 0.35355339f,  0.41573481f,  0.19134172f, -0.09754516f);
    dk[2] = sel4(kr, 0.35355339f,  0.27778512f, -0.19134172f, -0.49039264f);
    dk[3] = sel4(kr, 0.35355339f,  0.09754516f, -0.46193977f, -0.27778512f);
    dk[4] = sel4(kr, 0.35355339f, -0.09754516f, -0.46193977f,  0.27778512f);
    dk[5] = sel4(kr, 0.35355339f, -0.27778512f, -0.19134172f,  0.49039264f);
    dk[6] = sel4(kr, 0.35355339f, -0.41573481f,  0.19134172f,  0.09754516f);
    dk[7] = sel4(kr, 0.35355339f, -0.49039264f,  0.46193977f, -0.41573481f);

    const float* xp = x + (((size_t)b * 3) * 512 + (size_t)gy * 8) * 512 + p * 8;
    float tmp[8] = {0.f,0.f,0.f,0.f,0.f,0.f,0.f,0.f};
    #pragma unroll
    for (int i = 0; i < 8; ++i) {
      const float* r = xp + i * 512;
      float4 ra = ((const float4*)r)[0],           rb = ((const float4*)r)[1];
      float4 ga = ((const float4*)(r + 262144))[0], gb = ((const float4*)(r + 262144))[1];
      float4 ba = ((const float4*)(r + 524288))[0], bb = ((const float4*)(r + 524288))[1];
      float g0 = 0.299f*ra.x + 0.587f*ga.x + 0.114f*ba.x;
      float g1 = 0.299f*ra.y + 0.587f*ga.y + 0.114f*ba.y;
      float g2 = 0.299f*ra.z + 0.587f*ga.z + 0.114f*ba.z;
      float g3 = 0.299f*ra.w + 0.587f*ga.w + 0.114f*ba.w;
      float g4 = 0.299f*rb.x + 0.587f*gb.x + 0.114f*bb.x;
      float g5 = 0.299f*rb.y + 0.587f*gb.y + 0.114f*bb.y;
      float g6 = 0.299f*rb.z + 0.587f*gb.z + 0.114f*bb.z;
      float g7 = 0.299f*rb.w + 0.587f*gb.w + 0.114f*bb.w;
      float d = dk[i];
      tmp[0] = fmaf(d, g0, tmp[0]); tmp[1] = fmaf(d, g1, tmp[1]);
      tmp[2] = fmaf(d, g2, tmp[2]); tmp[3] = fmaf(d, g3, tmp[3]);
      tmp[4] = fmaf(d, g4, tmp[4]); tmp[5] = fmaf(d, g5, tmp[5]);
      tmp[6] = fmaf(d, g6, tmp[6]); tmp[7] = fmaf(d, g7, tmp[7]);
    }
    // stage 2: compile-time D4[l][j] -> literal FMAs
    const float D4c[4][8] = {
      { 0.35355339f, 0.35355339f, 0.35355339f, 0.35355339f,
        0.35355339f, 0.35355339f, 0.35355339f, 0.35355339f},
      { 0.49039264f, 0.41573481f, 0.27778512f, 0.09754516f,
       -0.09754516f,-0.27778512f,-0.41573481f,-0.49039264f},
      { 0.46193977f, 0.19134172f,-0.19134172f,-0.46193977f,
       -0.46193977f,-0.19134172f, 0.19134172f, 0.46193977f},
      { 0.41573481f,-0.09754516f,-0.49039264f,-0.27778512f,
        0.27778512f, 0.49039264f, 0.09754516f,-0.41573481f}
    };
    float cc[4] = {0.f, 0.f, 0.f, 0.f};
    #pragma unroll
    for (int l = 0; l < 4; ++l)
      #pragma unroll
      for (int j = 0; j < 8; ++j)
        cc[l] = fmaf(tmp[j], D4c[l][j], cc[l]);
    ushort4 fv;
    fv.x = f2bf(cc[0]); fv.y = f2bf(cc[1]); fv.z = f2bf(cc[2]); fv.w = f2bf(cc[3]);
    *(ushort4*)(featS + p * FSTRIDE + kr * 4) = fv;   // 8-B aligned ds_write_b64
  }
  __syncthreads();

  // ---- GEMM1 (feats[64x16] @ W1[16x256] + b1, relu) -> h bf16 LDS ----
  for (int mt = 0; mt < 4; ++mt) {
    frag8 a = {0,0,0,0,0,0,0,0};
    if (quad < 2)
      a = *(const frag8*)(featS + (mt * 16 + l16) * FSTRIDE + quad * 8); // b128, 16-B aligned
    for (int nt = 0; nt < 4; ++nt) {
      f32x4 acc = {b1v[nt], b1v[nt], b1v[nt], b1v[nt]};
      acc = __builtin_amdgcn_mfma_f32_16x16x32_bf16(a, bW1[nt], acc, 0, 0, 0);
      int n = (w * 4 + nt) * 16 + l16;
      #pragma unroll
      for (int rg = 0; rg < 4; ++rg) {
        float v = acc[rg];
        v = v > 0.f ? v : 0.f;
        int m = mt * 16 + quad * 4 + rg;
        hS[m * HSTRIDE + n] = f2bf(v);
      }
    }
  }
  __syncthreads();

  // ---- GEMM2 (h[64x256] @ W2[256x64] + b2) -> direct global float4 stores ----
  for (int mt = 0; mt < 4; ++mt) {
    f32x4 acc = {b2v, b2v, b2v, b2v};
    const u16* hrow = hS + (mt * 16 + l16) * HSTRIDE;
    #pragma unroll
    for (int s = 0; s < 8; ++s) {
      frag8 a = *(const frag8*)(hrow + s * 32 + quad * 8);  // ds_read_b128
      acc = __builtin_amdgcn_mfma_f32_16x16x32_bf16(a, bW2[s], acc, 0, 0, 0);
    }
    // D layout: m = quad*4+rg -> gx contiguous over rg => float4 store
    float* dst = out + (((size_t)b * 64 + n3) * 64 + gy) * 64 + mt * 16 + quad * 4;
    float4 v; v.x = acc[0]; v.y = acc[1]; v.z = acc[2]; v.w = acc[3];
    *(float4*)dst = v;
  }
}

extern "C" void kernel_launch(void* const* d_in, const int* in_sizes, int n_in,
                              void* d_out, int out_size, void* d_ws, size_t ws_size,
                              hipStream_t stream) {
  const float* x  = (const float*)d_in[0];
  const float* W1 = (const float*)d_in[1];
  const float* b1 = (const float*)d_in[2];
  const float* W2 = (const float*)d_in[3];
  const float* b2 = (const float*)d_in[4];
  float* out = (float*)d_out;
  dim3 grid(64, 32, 1);   // (gy, b)
  dct_mlp_fused<<<grid, dim3(256, 1, 1), 0, stream>>>(x, W1, b1, W2, b2, out);
}

// Round 5
// 201.565 us; speedup vs baseline: 1.4607x; 1.0752x over previous
//
#include <hip/hip_runtime.h>

typedef unsigned short u16;
typedef __attribute__((ext_vector_type(8))) short frag8;   // 8 bf16 (4 VGPRs)
typedef __attribute__((ext_vector_type(4))) float f32x4;   // MFMA accumulator

__device__ __forceinline__ u16 f2bf(float f) {
  unsigned u; __builtin_memcpy(&u, &f, 4);
  u = (u + 0x7FFFu + ((u >> 16) & 1u)) >> 16;   // RNE
  return (u16)u;
}
__device__ __forceinline__ float sel4(int s, float a, float b, float c, float d) {
  return s == 0 ? a : (s == 1 ? b : (s == 2 ? c : d));
}

#define FSTRIDE 24    // feats row stride (bf16 units): 48 B, b128 reads 16-B aligned
#define HSTRIDE 264   // h row stride (bf16 units), +8 pad
#define ESTRIDE 68    // embT row stride (f32 units)
// LDS: hS [64][264] bf16 @ 0 (33792 B); feats [64][24] bf16 @ 33792 (3072 B)
// embT [64][68] f32 (17408 B) aliases hS (dead when written)
#define SMEM_BYTES 36864

__global__ __launch_bounds__(256, 4)
void dct_mlp_fused(const float* __restrict__ x,
                   const float* __restrict__ W1, const float* __restrict__ b1,
                   const float* __restrict__ W2, const float* __restrict__ b2,
                   float* __restrict__ out) {
  __shared__ __align__(16) char smem[SMEM_BYTES];
  u16*   hS    = (u16*)smem;               // [64][264]
  u16*   featS = (u16*)(smem + 33792);     // [64][24]
  float* embS  = (float*)smem;             // [64][68], aliases hS

  const int t    = threadIdx.x;
  const int lane = t & 63;
  const int w    = t >> 6;          // wave 0..3
  const int quad = lane >> 4;       // 0..3
  const int l16  = lane & 15;

  // ---- Weight fragments: loaded ONCE per block (2 tiles amortize) ----
  // GEMM1 (swapped: h^T = W1^T @ feats^T). A-frag = W1^T tile: same register
  // content as the B-frag of the unswapped form. Wave w owns 256-dim tiles
  // w*4+nt.
  frag8 aW1[4];
  f32x4 b1v4[4];
  for (int nt = 0; nt < 4; ++nt) {
    int n = (w * 4 + nt) * 16 + l16;
    frag8 f;
    for (int j = 0; j < 8; ++j) {
      int k = quad * 8 + j;
      f[j] = (k < 16) ? (short)f2bf(W1[k * 256 + n]) : (short)0;
    }
    aW1[nt] = f;
    const float4 bv = *(const float4*)(b1 + (w * 4 + nt) * 16 + quad * 4);
    b1v4[nt][0] = bv.x; b1v4[nt][1] = bv.y; b1v4[nt][2] = bv.z; b1v4[nt][3] = bv.w;
  }
  // GEMM2 B-frags: wave w owns channel tile w of N=64; K=256 in 8 steps of 32.
  frag8 bW2[8];
  const int n3 = w * 16 + l16;      // output channel
  for (int s = 0; s < 8; ++s) {
    frag8 f;
    for (int j = 0; j < 8; ++j) {
      int c = s * 32 + quad * 8 + j;
      f[j] = (short)f2bf(W2[c * 64 + n3]);
    }
    bW2[s] = f;
  }
  const float b2v = b2[n3];

  for (int it = 0; it < 2; ++it) {
    const int tile = blockIdx.x + 1024 * it;
    const int gy = tile & 63;
    const int b  = tile >> 6;

    // ---- Phase A: register DCT straight from global ----
    {
      const int p  = t >> 2;
      const int kr = t & 3;
      float dk[8];
      dk[0] = sel4(kr, 0.35355339f,  0.49039264f,  0.46193977f,  0.41573481f);
      dk[1] = sel4(kr, 0.35355339f,  0.41573481f,  0.19134172f, -0.09754516f);
      dk[2] = sel4(kr, 0.35355339f,  0.27778512f, -0.19134172f, -0.49039264f);
      dk[3] = sel4(kr, 0.35355339f,  0.09754516f, -0.46193977f, -0.27778512f);
      dk[4] = sel4(kr, 0.35355339f, -0.09754516f, -0.46193977f,  0.27778512f);
      dk[5] = sel4(kr, 0.35355339f, -0.27778512f, -0.19134172f,  0.49039264f);
      dk[6] = sel4(kr, 0.35355339f, -0.41573481f,  0.19134172f,  0.09754516f);
      dk[7] = sel4(kr, 0.35355339f, -0.49039264f,  0.46193977f, -0.41573481f);

      const float* xp = x + (((size_t)b * 3) * 512 + (size_t)gy * 8) * 512 + p * 8;
      float tmp[8] = {0.f,0.f,0.f,0.f,0.f,0.f,0.f,0.f};
      #pragma unroll
      for (int i = 0; i < 8; ++i) {
        const float* r = xp + i * 512;
        float4 ra = ((const float4*)r)[0],            rb = ((const float4*)r)[1];
        float4 ga = ((const float4*)(r + 262144))[0], gb = ((const float4*)(r + 262144))[1];
        float4 ba = ((const float4*)(r + 524288))[0], bb = ((const float4*)(r + 524288))[1];
        float g0 = 0.299f*ra.x + 0.587f*ga.x + 0.114f*ba.x;
        float g1 = 0.299f*ra.y + 0.587f*ga.y + 0.114f*ba.y;
        float g2 = 0.299f*ra.z + 0.587f*ga.z + 0.114f*ba.z;
        float g3 = 0.299f*ra.w + 0.587f*ga.w + 0.114f*ba.w;
        float g4 = 0.299f*rb.x + 0.587f*gb.x + 0.114f*bb.x;
        float g5 = 0.299f*rb.y + 0.587f*gb.y + 0.114f*bb.y;
        float g6 = 0.299f*rb.z + 0.587f*gb.z + 0.114f*bb.z;
        float g7 = 0.299f*rb.w + 0.587f*gb.w + 0.114f*bb.w;
        float d = dk[i];
        tmp[0] = fmaf(d, g0, tmp[0]); tmp[1] = fmaf(d, g1, tmp[1]);
        tmp[2] = fmaf(d, g2, tmp[2]); tmp[3] = fmaf(d, g3, tmp[3]);
        tmp[4] = fmaf(d, g4, tmp[4]); tmp[5] = fmaf(d, g5, tmp[5]);
        tmp[6] = fmaf(d, g6, tmp[6]); tmp[7] = fmaf(d, g7, tmp[7]);
      }
      const float D4c[4][8] = {
        { 0.35355339f, 0.35355339f, 0.35355339f, 0.35355339f,
          0.35355339f, 0.35355339f, 0.35355339f, 0.35355339f},
        { 0.49039264f, 0.41573481f, 0.27778512f, 0.09754516f,
         -0.09754516f,-0.27778512f,-0.41573481f,-0.49039264f},
        { 0.46193977f, 0.19134172f,-0.19134172f,-0.46193977f,
         -0.46193977f,-0.19134172f, 0.19134172f, 0.46193977f},
        { 0.41573481f,-0.09754516f,-0.49039264f,-0.27778512f,
          0.27778512f, 0.49039264f, 0.09754516f,-0.41573481f}
      };
      float cc[4] = {0.f, 0.f, 0.f, 0.f};
      #pragma unroll
      for (int l = 0; l < 4; ++l)
        #pragma unroll
        for (int j = 0; j < 8; ++j)
          cc[l] = fmaf(tmp[j], D4c[l][j], cc[l]);
      ushort4 fv;
      fv.x = f2bf(cc[0]); fv.y = f2bf(cc[1]); fv.z = f2bf(cc[2]); fv.w = f2bf(cc[3]);
      *(ushort4*)(featS + p * FSTRIDE + kr * 4) = fv;
    }
    __syncthreads();

    // ---- GEMM1 (swapped): D[m=k256][n=patch]; lane's 4 outputs k-contiguous ----
    for (int pt = 0; pt < 4; ++pt) {
      frag8 bf = {0,0,0,0,0,0,0,0};
      if (quad < 2)
        bf = *(const frag8*)(featS + (pt * 16 + l16) * FSTRIDE + quad * 8); // b128
      for (int nt = 0; nt < 4; ++nt) {
        f32x4 acc = b1v4[nt];
        acc = __builtin_amdgcn_mfma_f32_16x16x32_bf16(aW1[nt], bf, acc, 0, 0, 0);
        ushort4 hv;
        hv.x = f2bf(acc[0] > 0.f ? acc[0] : 0.f);
        hv.y = f2bf(acc[1] > 0.f ? acc[1] : 0.f);
        hv.z = f2bf(acc[2] > 0.f ? acc[2] : 0.f);
        hv.w = f2bf(acc[3] > 0.f ? acc[3] : 0.f);
        *(ushort4*)(hS + (pt * 16 + l16) * HSTRIDE + (w * 4 + nt) * 16 + quad * 4) = hv;
      }
    }
    __syncthreads();

    // ---- GEMM2 (h[64x256] @ W2[256x64] + b2) ----
    f32x4 accs[4];
    for (int mt = 0; mt < 4; ++mt) {
      f32x4 acc = {b2v, b2v, b2v, b2v};
      const u16* hrow = hS + (mt * 16 + l16) * HSTRIDE;
      #pragma unroll
      for (int s = 0; s < 8; ++s) {
        frag8 a = *(const frag8*)(hrow + s * 32 + quad * 8);  // ds_read_b128
        acc = __builtin_amdgcn_mfma_f32_16x16x32_bf16(a, bW2[s], acc, 0, 0, 0);
      }
      accs[mt] = acc;
    }
    __syncthreads();   // hS reads done; embS may now overwrite it

    for (int mt = 0; mt < 4; ++mt) {
      float4 v; v.x = accs[mt][0]; v.y = accs[mt][1]; v.z = accs[mt][2]; v.w = accs[mt][3];
      *(float4*)(embS + n3 * ESTRIDE + mt * 16 + quad * 4) = v;
    }
    __syncthreads();

    // ---- Coalesced epilogue: wave stores contiguous 4 KB per instruction ----
    {
      const int ch = t >> 2;   // 0..63
      const int cc = t & 3;    // 16-float chunk
      const float* src = embS + ch * ESTRIDE + cc * 16;
      float* dst = out + ((((size_t)b * 64 + ch) * 64) + gy) * 64 + cc * 16;
      #pragma unroll
      for (int q = 0; q < 4; ++q)
        ((float4*)dst)[q] = ((const float4*)src)[q];
    }
    // next iteration's featS writes don't alias embS; the phase-A barrier
    // orders these epilogue reads before the next hS overwrite.
  }
}

extern "C" void kernel_launch(void* const* d_in, const int* in_sizes, int n_in,
                              void* d_out, int out_size, void* d_ws, size_t ws_size,
                              hipStream_t stream) {
  const float* x  = (const float*)d_in[0];
  const float* W1 = (const float*)d_in[1];
  const float* b1 = (const float*)d_in[2];
  const float* W2 = (const float*)d_in[3];
  const float* b2 = (const float*)d_in[4];
  float* out = (float*)d_out;
  dct_mlp_fused<<<dim3(1024, 1, 1), dim3(256, 1, 1), 0, stream>>>(x, W1, b1, W2, b2, out);
}